// Round 6
// baseline (1877.533 us; speedup 1.0000x reference)
//
#include <hip/hip_runtime.h>

// HGNN layer, v6 — all float32. Exact data-dependent edge widths via a flat
// (b,p,m) pair list (no per-edge cap). B=4, N=2304, C=64.

#define HB    4
#define HN    2304
#define HC    64
#define HK    11             // K_NEIGS + 1
#define HL    48
#define HW    22             // windows per dim
#define HE2   484            // 22*22 local edges
#define HE    (HN + HE2)
#define HRPB  4
#define NPAIRS (HB * HK * HN)   // sum of Dv == 11*N per batch, exact

__global__ void hg6_sentinel(float* out, int n) {
    int i = blockIdx.x * 256 + threadIdx.x;
    if (i < n) out[i] = 12345.0f;
}

__global__ void hg6_init(int* Dv, int* indeg, int* paircnt, float* bnsum, float* bnss) {
    int i = blockIdx.x * 256 + threadIdx.x;
    if (i < HB * HN) { Dv[i] = 0; indeg[i] = 0; }
    if (i == 0) *paircnt = 0;
    if (i < HC) { bnsum[i] = 0.f; bnss[i] = 0.f; }
}

// -------- linear h1 = x W^T + b, xsq, f32 transpose -----------------------
__global__ __launch_bounds__(64) void hg6_linear(const float* x, const float* W,
                                                 const float* bias, float* h1,
                                                 float* xsq, float* xT) {
    int row = blockIdx.x;            // 0..B*N-1
    int t = threadIdx.x;
    __shared__ float xr[HC];
    float v = x[row * HC + t];
    xr[t] = v;
    __syncthreads();
    float sq = v * v;
    #pragma unroll
    for (int o = 32; o > 0; o >>= 1) sq += __shfl_xor(sq, o);
    if (t == 0) xsq[row] = sq;
    int b = row / HN, n = row % HN;
    xT[(b * HC + t) * HN + n] = v;
    float acc = bias[t];
    #pragma unroll 8
    for (int c = 0; c < HC; c++) acc += xr[c] * W[t * HC + c];
    h1[row * HC + t] = acc;
}

// -------- kNN body: distance row in LDS + iterative stable argmin ---------
__device__ __forceinline__ void hg6_knn_body(const float* xT, const float* xsq,
                                             int* Dv, int* indeg,
                                             unsigned int* pairs, int* paircnt,
                                             int sel) {
    __shared__ float d[HRPB][HN];      // 36 KB
    __shared__ float xr[HRPB][HC];
    __shared__ float redv[4];
    __shared__ int   redi[4];
    const int t = threadIdx.x;
    const int b = blockIdx.x / (HN / HRPB);
    const int n0 = (blockIdx.x % (HN / HRPB)) * HRPB;
    xr[t >> 6][t & 63] = xT[(b * HC + (t & 63)) * HN + n0 + (t >> 6)];
    __syncthreads();
    float xs[HRPB];
    #pragma unroll
    for (int r = 0; r < HRPB; r++) xs[r] = xsq[b * HN + n0 + r];
    for (int m = t; m < HN; m += 256) {          // 9 iterations
        float dot0 = 0.f, dot1 = 0.f, dot2 = 0.f, dot3 = 0.f;
        #pragma unroll 8
        for (int c = 0; c < HC; c++) {
            float xv = xT[(b * HC + c) * HN + m];
            dot0 += xr[0][c] * xv;
            dot1 += xr[1][c] * xv;
            dot2 += xr[2][c] * xv;
            dot3 += xr[3][c] * xv;
        }
        float xsm = xsq[b * HN + m];
        d[0][m] = xs[0] + xsm - 2.f * dot0;
        d[1][m] = xs[1] + xsm - 2.f * dot1;
        d[2][m] = xs[2] + xsm - 2.f * dot2;
        d[3][m] = xs[3] + xsm - 2.f * dot3;
    }
    __syncthreads();
    for (int r = 0; r < HRPB; r++) {
        const int p = n0 + r;
        const int kk = sel ? max(Dv[b * HN + p], 1) : HK;   // exact width, no cap
        for (int j = 0; j < kk; j++) {
            float bv = 3.0e38f; int bi = HN;
            for (int m = t; m < HN; m += 256) {
                float v = d[r][m];
                if (v < bv) { bv = v; bi = m; }
            }
            #pragma unroll
            for (int o = 32; o > 0; o >>= 1) {   // lexicographic (value, index) min
                float ov = __shfl_xor(bv, o); int oi = __shfl_xor(bi, o);
                if (ov < bv || (ov == bv && oi < bi)) { bv = ov; bi = oi; }
            }
            if ((t & 63) == 0) { redv[t >> 6] = bv; redi[t >> 6] = bi; }
            __syncthreads();
            if (t == 0) {
                for (int w = 1; w < 4; w++)
                    if (redv[w] < bv || (redv[w] == bv && redi[w] < bi)) { bv = redv[w]; bi = redi[w]; }
                if (bi >= 0 && bi < HN) {
                    d[r][bi] = 3.0e38f;          // remove chosen
                    if (sel) {
                        atomicAdd(&indeg[b * HN + bi], 1);
                        int pos = atomicAdd(paircnt, 1);
                        if (pos < NPAIRS)
                            pairs[pos] = ((unsigned)b << 24) | ((unsigned)p << 12) | (unsigned)bi;
                    } else {
                        atomicAdd(&Dv[b * HN + bi], 1);
                    }
                }
            }
            __syncthreads();
        }
    }
}

__global__ __launch_bounds__(256) void hg6_knn_count(const float* xT, const float* xsq,
                                                     int* Dv, int* indeg,
                                                     unsigned int* pairs, int* paircnt) {
    hg6_knn_body(xT, xsq, Dv, indeg, pairs, paircnt, 0);
}

__global__ __launch_bounds__(256) void hg6_knn_select(const float* xT, const float* xsq,
                                                      int* Dv, int* indeg,
                                                      unsigned int* pairs, int* paircnt) {
    hg6_knn_body(xT, xsq, Dv, indeg, pairs, paircnt, 1);
}

__device__ __forceinline__ int hg6_lo(int rc) { return max(0, (rc - 3) / 2); }
__device__ __forceinline__ int hg6_hi(int rc) { return min(HW - 1, rc / 2); }

// -------- y = Dv^-1/2 * h1 (in place) -------------------------------------
__global__ __launch_bounds__(256) void hg6_scale(float* h1, const int* indeg) {
    int i = blockIdx.x * 256 + threadIdx.x;
    int node = i >> 6;
    int n = node % HN;
    int r = n / HL, c = n % HL;
    int cover = max(0, hg6_hi(r) - hg6_lo(r) + 1) * max(0, hg6_hi(c) - hg6_lo(c) + 1);
    int dvn = max(indeg[node] + cover, 1);
    h1[i] *= rsqrtf((float)dvn);
}

// -------- zero z (aliases dead xT; must run after knn passes) -------------
__global__ void hg6_zero_z(float* z) {
    int i = blockIdx.x * 256 + threadIdx.x;
    if (i < HB * HE * HC) z[i] = 0.f;
}

// -------- z[p] += y[m] / DE[p] over the pair list (atomic) ----------------
__global__ __launch_bounds__(256) void hg6_zscatter(const unsigned int* pairs, const int* Dv,
                                                    const float* y, float* z) {
    int idx = (blockIdx.x * 256 + threadIdx.x) >> 6;   // one wave per pair
    int lane = threadIdx.x & 63;
    if (idx >= NPAIRS) return;
    unsigned int pk = pairs[idx];
    int b = pk >> 24, p = (pk >> 12) & 0xFFF, m = pk & 0xFFF;
    float invde = 1.f / (float)max(Dv[b * HN + p], 1);
    atomicAdd(&z[(b * HE + p) * HC + lane], y[(b * HN + m) * HC + lane] * invde);
}

// -------- window-edge means (direct, non-atomic) --------------------------
__global__ __launch_bounds__(256) void hg6_zwin(const float* y, float* z) {
    int wave = (blockIdx.x * 256 + threadIdx.x) >> 6;  // one wave per (b, window)
    int lane = threadIdx.x & 63;
    if (wave >= HB * HE2) return;
    int b = wave / HE2, w = wave % HE2;
    int wr = w / HW, wc = w % HW;
    float acc = 0.f;
    #pragma unroll
    for (int i = 0; i < 5; i++)
        #pragma unroll
        for (int j = 0; j < 5; j++)
            acc += y[(b * HN + (wr * 2 + i) * HL + wc * 2 + j) * HC + lane];
    z[(b * HE + HN + w) * HC + lane] = acc * (1.f / 25.f);
}

// -------- zero h2 (aliases h1; must run after zscatter/zwin) --------------
__global__ void hg6_zero_h2(float* h2) {
    int i = blockIdx.x * 256 + threadIdx.x;
    if (i < HB * HN * HC) h2[i] = 0.f;
}

// -------- h2[m] += z[p] over the pair list (atomic) -----------------------
__global__ __launch_bounds__(256) void hg6_gscatter(const unsigned int* pairs,
                                                    const float* z, float* h2) {
    int idx = (blockIdx.x * 256 + threadIdx.x) >> 6;
    int lane = threadIdx.x & 63;
    if (idx >= NPAIRS) return;
    unsigned int pk = pairs[idx];
    int b = pk >> 24, p = (pk >> 12) & 0xFFF, m = pk & 0xFFF;
    atomicAdd(&h2[(b * HN + m) * HC + lane], z[(b * HE + p) * HC + lane]);
}

// -------- add window contributions + final Dv^-1/2 scale ------------------
__global__ __launch_bounds__(256) void hg6_gfinish(const float* z, const int* indeg, float* h2) {
    int wave = (blockIdx.x * 256 + threadIdx.x) >> 6;  // one wave per (b, node)
    int lane = threadIdx.x & 63;
    int b = wave / HN, n = wave % HN;
    int g = b * HN + n;
    float acc = h2[g * HC + lane];
    int r = n / HL, c = n % HL;
    int rlo = hg6_lo(r), rhi = hg6_hi(r), clo = hg6_lo(c), chi = hg6_hi(c);
    for (int wr = rlo; wr <= rhi; wr++)
        for (int wc = clo; wc <= chi; wc++)
            acc += z[(b * HE + HN + wr * HW + wc) * HC + lane];
    int dvn = max(indeg[g] + max(0, rhi - rlo + 1) * max(0, chi - clo + 1), 1);
    h2[g * HC + lane] = acc * rsqrtf((float)dvn);
}

// -------- BN stats --------------------------------------------------------
__global__ __launch_bounds__(256) void hg6_bnstats(const float* h2, float* bnsum, float* bnss) {
    int t = threadIdx.x;
    int c = t & 63, rg = t >> 6;
    int row0 = blockIdx.x * 36;      // 256 blocks * 36 rows = 9216
    float s = 0.f, ss = 0.f;
    for (int r = rg; r < 36; r += 4) {
        float v = h2[(row0 + r) * HC + c];
        s += v; ss += v * v;
    }
    __shared__ float ls[256], lss[256];
    ls[t] = s; lss[t] = ss;
    __syncthreads();
    if (t < 64) {
        s  = ls[t]  + ls[t + 64]  + ls[t + 128]  + ls[t + 192];
        ss = lss[t] + lss[t + 64] + lss[t + 128] + lss[t + 192];
        atomicAdd(&bnsum[t], s);
        atomicAdd(&bnss[t], ss);
    }
}

// -------- BN + ReLU + residual --------------------------------------------
__global__ __launch_bounds__(256) void hg6_final(const float* h2, const float* x,
                                                 const float* gamma, const float* beta,
                                                 const float* bnsum, const float* bnss,
                                                 float* out) {
    int i = blockIdx.x * 256 + threadIdx.x;
    int c = i & 63;
    const float M = (float)(HB * HN);
    float mean = bnsum[c] / M;
    float var  = bnss[c] / M - mean * mean;
    float inv  = rsqrtf(var + 1e-5f);
    float h = gamma[c] * (h2[i] - mean) * inv + beta[c];
    out[i] = fmaxf(h, 0.f) + x[i];
}

extern "C" void kernel_launch(void* const* d_in, const int* in_sizes, int n_in,
                              void* d_out, int out_size, void* d_ws, size_t ws_size,
                              hipStream_t stream) {
    const float* x     = (const float*)d_in[0];
    const float* W     = (const float*)d_in[1];
    const float* bias  = (const float*)d_in[2];
    const float* gamma = (const float*)d_in[3];
    const float* beta  = (const float*)d_in[4];
    float* out = (float*)d_out;
    (void)in_sizes; (void)n_in;

    char* ws = (char*)d_ws;
    size_t off = 0;
    float*        xsq     = (float*)(ws + off);        off += (size_t)HB * HN * 4;
    float*        h1      = (float*)(ws + off);        off += (size_t)HB * HN * HC * 4;  // also h2
    int*          Dv      = (int*)(ws + off);          off += (size_t)HB * HN * 4;
    int*          indeg   = (int*)(ws + off);          off += (size_t)HB * HN * 4;
    unsigned int* pairs   = (unsigned int*)(ws + off); off += (size_t)NPAIRS * 4;
    float*        bnsum   = (float*)(ws + off);        off += 256;
    float*        bnss    = (float*)(ws + off);        off += 256;
    int*          paircnt = (int*)(ws + off);          off += 256;
    float*        xT      = (float*)(ws + off);        // z aliases xT (dead after kNN)
    float*        z       = (float*)(ws + off);
    off += (size_t)HB * HE * HC * 4;   // max(xT, z) = z
    float*        h2      = h1;        // h1/y dead after zscatter+zwin

    if (ws_size < off) {
        hg6_sentinel<<<(out_size + 255) / 256, 256, 0, stream>>>(out, out_size);
        return;
    }

    hg6_init<<<(HB * HN + 255) / 256, 256, 0, stream>>>(Dv, indeg, paircnt, bnsum, bnss);
    hg6_linear<<<HB * HN, 64, 0, stream>>>(x, W, bias, h1, xsq, xT);
    hg6_knn_count<<<HB * (HN / HRPB), 256, 0, stream>>>(xT, xsq, Dv, indeg, pairs, paircnt);
    hg6_knn_select<<<HB * (HN / HRPB), 256, 0, stream>>>(xT, xsq, Dv, indeg, pairs, paircnt);
    hg6_scale<<<(HB * HN * HC) / 256, 256, 0, stream>>>(h1, indeg);
    hg6_zero_z<<<(HB * HE * HC + 255) / 256, 256, 0, stream>>>(z);
    hg6_zscatter<<<(NPAIRS * 64 + 255) / 256, 256, 0, stream>>>(pairs, Dv, h1, z);
    hg6_zwin<<<(HB * HE2 * 64 + 255) / 256, 256, 0, stream>>>(h1, z);
    hg6_zero_h2<<<(HB * HN * HC + 255) / 256, 256, 0, stream>>>(h2);
    hg6_gscatter<<<(NPAIRS * 64 + 255) / 256, 256, 0, stream>>>(pairs, z, h2);
    hg6_gfinish<<<(HB * HN * 64 + 255) / 256, 256, 0, stream>>>(z, indeg, h2);
    hg6_bnstats<<<256, 256, 0, stream>>>(h2, bnsum, bnss);
    hg6_final<<<(HB * HN * HC) / 256, 256, 0, stream>>>(h2, x, gamma, beta, bnsum, bnss, out);
}

// Round 7
// 673.884 us; speedup vs baseline: 2.7861x; 2.7861x over previous
//
#include <hip/hip_runtime.h>

// HGNN layer, v7 — fp32. v6 structure, but kNN selection is wave-per-row
// (no barriers in the selection loop; the v6 version was barrier-bound at
// VALUBusy ~9.5%). B=4, N=2304, C=64.

#define HB    4
#define HN    2304
#define HC    64
#define HK    11             // K_NEIGS + 1
#define HL    48
#define HW    22             // windows per dim
#define HE2   484            // 22*22 local edges
#define HE    (HN + HE2)
#define HRPB  4              // rows per block == waves per block
#define NPAIRS (HB * HK * HN)   // sum of Dv == 11*N per batch, exact
#define PAIR_INVALID 0xFFFFFFFFu

__global__ void hg7_sentinel(float* out, int n) {
    int i = blockIdx.x * 256 + threadIdx.x;
    if (i < n) out[i] = 12345.0f;
}

__global__ void hg7_init(int* Dv, int* indeg, int* paircnt, float* bnsum, float* bnss) {
    int i = blockIdx.x * 256 + threadIdx.x;
    if (i < HB * HN) { Dv[i] = 0; indeg[i] = 0; }
    if (i == 0) *paircnt = 0;
    if (i < HC) { bnsum[i] = 0.f; bnss[i] = 0.f; }
}

// -------- linear h1 = x W^T + b, xsq, f32 transpose -----------------------
__global__ __launch_bounds__(64) void hg7_linear(const float* x, const float* W,
                                                 const float* bias, float* h1,
                                                 float* xsq, float* xT) {
    int row = blockIdx.x;            // 0..B*N-1
    int t = threadIdx.x;
    __shared__ float xr[HC];
    float v = x[row * HC + t];
    xr[t] = v;
    __syncthreads();
    float sq = v * v;
    #pragma unroll
    for (int o = 32; o > 0; o >>= 1) sq += __shfl_xor(sq, o);
    if (t == 0) xsq[row] = sq;
    int b = row / HN, n = row % HN;
    xT[(b * HC + t) * HN + n] = v;
    float acc = bias[t];
    #pragma unroll 8
    for (int c = 0; c < HC; c++) acc += xr[c] * W[t * HC + c];
    h1[row * HC + t] = acc;
}

// -------- kNN: block-cooperative distances, wave-per-row selection --------
// sel=0: pick 11 nearest per row (incl self), count Dv[neighbor].
// sel=1: pick Dv[row] nearest, emit (b,p,m) pairs, count node in-degree.
__device__ __forceinline__ void hg7_knn_body(const float* xT, const float* xsq,
                                             int* Dv, int* indeg,
                                             unsigned int* pairs, int* paircnt,
                                             int sel) {
    __shared__ float d[HRPB][HN];      // 36 KB
    __shared__ float xr[HRPB][HC];
    const int t = threadIdx.x;
    const int b = blockIdx.x / (HN / HRPB);
    const int n0 = (blockIdx.x % (HN / HRPB)) * HRPB;
    xr[t >> 6][t & 63] = xT[(b * HC + (t & 63)) * HN + n0 + (t >> 6)];
    __syncthreads();
    float xs[HRPB];
    #pragma unroll
    for (int r = 0; r < HRPB; r++) xs[r] = xsq[b * HN + n0 + r];
    for (int m = t; m < HN; m += 256) {          // 9 iterations
        float dot0 = 0.f, dot1 = 0.f, dot2 = 0.f, dot3 = 0.f;
        #pragma unroll 8
        for (int c = 0; c < HC; c++) {
            float xv = xT[(b * HC + c) * HN + m];
            dot0 += xr[0][c] * xv;
            dot1 += xr[1][c] * xv;
            dot2 += xr[2][c] * xv;
            dot3 += xr[3][c] * xv;
        }
        float xsm = xsq[b * HN + m];
        d[0][m] = xs[0] + xsm - 2.f * dot0;
        d[1][m] = xs[1] + xsm - 2.f * dot1;
        d[2][m] = xs[2] + xsm - 2.f * dot2;
        d[3][m] = xs[3] + xsm - 2.f * dot3;
    }
    __syncthreads();

    // ---- selection: wave r exclusively owns LDS row r; no block barriers.
    const int r = t >> 6;
    const int lane = t & 63;
    const int p = n0 + r;
    const int kk = sel ? max(Dv[b * HN + p], 1) : HK;
    int base = 0;
    if (sel) {                                   // reserve kk slots once
        if (lane == 0) base = atomicAdd(paircnt, kk);
        base = __shfl(base, 0);
    }
    const float2* drow = (const float2*)d[r];
    for (int j = 0; j < kk; j++) {
        float bv = 3.0e38f; int bi = HN;
        #pragma unroll
        for (int i = 0; i < HN / 128; i++) {     // 18 float2 reads, m ascending
            float2 v2 = drow[lane + 64 * i];
            int m = 2 * (lane + 64 * i);
            if (v2.x < bv) { bv = v2.x; bi = m; }
            if (v2.y < bv) { bv = v2.y; bi = m + 1; }
        }
        #pragma unroll
        for (int o = 32; o > 0; o >>= 1) {       // lexicographic (value, index) min
            float ov = __shfl_xor(bv, o); int oi = __shfl_xor(bi, o);
            if (ov < bv || (ov == bv && oi < bi)) { bv = ov; bi = oi; }
        }
        if (bi < HN && (bi & 63) == lane) d[r][bi] = 3.0e38f;   // remove chosen
        if (lane == 0) {
            if (bi < HN) {
                if (sel) {
                    atomicAdd(&indeg[b * HN + bi], 1);
                    int pos = base + j;
                    if (pos < NPAIRS)
                        pairs[pos] = ((unsigned)b << 24) | ((unsigned)p << 12) | (unsigned)bi;
                } else {
                    atomicAdd(&Dv[b * HN + bi], 1);
                }
            } else if (sel) {
                int pos = base + j;              // defensive: keep slot valid
                if (pos < NPAIRS) pairs[pos] = PAIR_INVALID;
            }
        }
    }
}

__global__ __launch_bounds__(256) void hg7_knn_count(const float* xT, const float* xsq,
                                                     int* Dv, int* indeg,
                                                     unsigned int* pairs, int* paircnt) {
    hg7_knn_body(xT, xsq, Dv, indeg, pairs, paircnt, 0);
}

__global__ __launch_bounds__(256) void hg7_knn_select(const float* xT, const float* xsq,
                                                      int* Dv, int* indeg,
                                                      unsigned int* pairs, int* paircnt) {
    hg7_knn_body(xT, xsq, Dv, indeg, pairs, paircnt, 1);
}

__device__ __forceinline__ int hg7_lo(int rc) { return max(0, (rc - 3) / 2); }
__device__ __forceinline__ int hg7_hi(int rc) { return min(HW - 1, rc / 2); }

// -------- y = Dv^-1/2 * h1 (in place) -------------------------------------
__global__ __launch_bounds__(256) void hg7_scale(float* h1, const int* indeg) {
    int i = blockIdx.x * 256 + threadIdx.x;
    int node = i >> 6;
    int n = node % HN;
    int r = n / HL, c = n % HL;
    int cover = max(0, hg7_hi(r) - hg7_lo(r) + 1) * max(0, hg7_hi(c) - hg7_lo(c) + 1);
    int dvn = max(indeg[node] + cover, 1);
    h1[i] *= rsqrtf((float)dvn);
}

// -------- zero z (aliases dead xT; must run after knn passes) -------------
__global__ void hg7_zero_z(float* z) {
    int i = blockIdx.x * 256 + threadIdx.x;
    if (i < HB * HE * HC) z[i] = 0.f;
}

// -------- z[p] += y[m] / DE[p] over the pair list (atomic) ----------------
__global__ __launch_bounds__(256) void hg7_zscatter(const unsigned int* pairs, const int* Dv,
                                                    const float* y, float* z) {
    int idx = (blockIdx.x * 256 + threadIdx.x) >> 6;   // one wave per pair
    int lane = threadIdx.x & 63;
    if (idx >= NPAIRS) return;
    unsigned int pk = pairs[idx];
    if (pk == PAIR_INVALID) return;
    int b = pk >> 24, p = (pk >> 12) & 0xFFF, m = pk & 0xFFF;
    float invde = 1.f / (float)max(Dv[b * HN + p], 1);
    atomicAdd(&z[(b * HE + p) * HC + lane], y[(b * HN + m) * HC + lane] * invde);
}

// -------- window-edge means (direct, non-atomic) --------------------------
__global__ __launch_bounds__(256) void hg7_zwin(const float* y, float* z) {
    int wave = (blockIdx.x * 256 + threadIdx.x) >> 6;  // one wave per (b, window)
    int lane = threadIdx.x & 63;
    if (wave >= HB * HE2) return;
    int b = wave / HE2, w = wave % HE2;
    int wr = w / HW, wc = w % HW;
    float acc = 0.f;
    #pragma unroll
    for (int i = 0; i < 5; i++)
        #pragma unroll
        for (int j = 0; j < 5; j++)
            acc += y[(b * HN + (wr * 2 + i) * HL + wc * 2 + j) * HC + lane];
    z[(b * HE + HN + w) * HC + lane] = acc * (1.f / 25.f);
}

// -------- zero h2 (aliases h1; must run after zscatter/zwin) --------------
__global__ void hg7_zero_h2(float* h2) {
    int i = blockIdx.x * 256 + threadIdx.x;
    if (i < HB * HN * HC) h2[i] = 0.f;
}

// -------- h2[m] += z[p] over the pair list (atomic) -----------------------
__global__ __launch_bounds__(256) void hg7_gscatter(const unsigned int* pairs,
                                                    const float* z, float* h2) {
    int idx = (blockIdx.x * 256 + threadIdx.x) >> 6;
    int lane = threadIdx.x & 63;
    if (idx >= NPAIRS) return;
    unsigned int pk = pairs[idx];
    if (pk == PAIR_INVALID) return;
    int b = pk >> 24, p = (pk >> 12) & 0xFFF, m = pk & 0xFFF;
    atomicAdd(&h2[(b * HN + m) * HC + lane], z[(b * HE + p) * HC + lane]);
}

// -------- add window contributions + final Dv^-1/2 scale ------------------
__global__ __launch_bounds__(256) void hg7_gfinish(const float* z, const int* indeg, float* h2) {
    int wave = (blockIdx.x * 256 + threadIdx.x) >> 6;  // one wave per (b, node)
    int lane = threadIdx.x & 63;
    int b = wave / HN, n = wave % HN;
    int g = b * HN + n;
    float acc = h2[g * HC + lane];
    int r = n / HL, c = n % HL;
    int rlo = hg7_lo(r), rhi = hg7_hi(r), clo = hg7_lo(c), chi = hg7_hi(c);
    for (int wr = rlo; wr <= rhi; wr++)
        for (int wc = clo; wc <= chi; wc++)
            acc += z[(b * HE + HN + wr * HW + wc) * HC + lane];
    int dvn = max(indeg[g] + max(0, rhi - rlo + 1) * max(0, chi - clo + 1), 1);
    h2[g * HC + lane] = acc * rsqrtf((float)dvn);
}

// -------- BN stats --------------------------------------------------------
__global__ __launch_bounds__(256) void hg7_bnstats(const float* h2, float* bnsum, float* bnss) {
    int t = threadIdx.x;
    int c = t & 63, rg = t >> 6;
    int row0 = blockIdx.x * 36;      // 256 blocks * 36 rows = 9216
    float s = 0.f, ss = 0.f;
    for (int r = rg; r < 36; r += 4) {
        float v = h2[(row0 + r) * HC + c];
        s += v; ss += v * v;
    }
    __shared__ float ls[256], lss[256];
    ls[t] = s; lss[t] = ss;
    __syncthreads();
    if (t < 64) {
        s  = ls[t]  + ls[t + 64]  + ls[t + 128]  + ls[t + 192];
        ss = lss[t] + lss[t + 64] + lss[t + 128] + lss[t + 192];
        atomicAdd(&bnsum[t], s);
        atomicAdd(&bnss[t], ss);
    }
}

// -------- BN + ReLU + residual --------------------------------------------
__global__ __launch_bounds__(256) void hg7_final(const float* h2, const float* x,
                                                 const float* gamma, const float* beta,
                                                 const float* bnsum, const float* bnss,
                                                 float* out) {
    int i = blockIdx.x * 256 + threadIdx.x;
    int c = i & 63;
    const float M = (float)(HB * HN);
    float mean = bnsum[c] / M;
    float var  = bnss[c] / M - mean * mean;
    float inv  = rsqrtf(var + 1e-5f);
    float h = gamma[c] * (h2[i] - mean) * inv + beta[c];
    out[i] = fmaxf(h, 0.f) + x[i];
}

extern "C" void kernel_launch(void* const* d_in, const int* in_sizes, int n_in,
                              void* d_out, int out_size, void* d_ws, size_t ws_size,
                              hipStream_t stream) {
    const float* x     = (const float*)d_in[0];
    const float* W     = (const float*)d_in[1];
    const float* bias  = (const float*)d_in[2];
    const float* gamma = (const float*)d_in[3];
    const float* beta  = (const float*)d_in[4];
    float* out = (float*)d_out;
    (void)in_sizes; (void)n_in;

    char* ws = (char*)d_ws;
    size_t off = 0;
    float*        xsq     = (float*)(ws + off);        off += (size_t)HB * HN * 4;
    float*        h1      = (float*)(ws + off);        off += (size_t)HB * HN * HC * 4;  // also h2
    int*          Dv      = (int*)(ws + off);          off += (size_t)HB * HN * 4;
    int*          indeg   = (int*)(ws + off);          off += (size_t)HB * HN * 4;
    unsigned int* pairs   = (unsigned int*)(ws + off); off += (size_t)NPAIRS * 4;
    float*        bnsum   = (float*)(ws + off);        off += 256;
    float*        bnss    = (float*)(ws + off);        off += 256;
    int*          paircnt = (int*)(ws + off);          off += 256;
    float*        xT      = (float*)(ws + off);        // z aliases xT (dead after kNN)
    float*        z       = (float*)(ws + off);
    off += (size_t)HB * HE * HC * 4;   // max(xT, z) = z
    float*        h2      = h1;        // h1/y dead after zscatter+zwin

    if (ws_size < off) {
        hg7_sentinel<<<(out_size + 255) / 256, 256, 0, stream>>>(out, out_size);
        return;
    }

    hg7_init<<<(HB * HN + 255) / 256, 256, 0, stream>>>(Dv, indeg, paircnt, bnsum, bnss);
    hg7_linear<<<HB * HN, 64, 0, stream>>>(x, W, bias, h1, xsq, xT);
    hg7_knn_count<<<HB * (HN / HRPB), 256, 0, stream>>>(xT, xsq, Dv, indeg, pairs, paircnt);
    hg7_knn_select<<<HB * (HN / HRPB), 256, 0, stream>>>(xT, xsq, Dv, indeg, pairs, paircnt);
    hg7_scale<<<(HB * HN * HC) / 256, 256, 0, stream>>>(h1, indeg);
    hg7_zero_z<<<(HB * HE * HC + 255) / 256, 256, 0, stream>>>(z);
    hg7_zscatter<<<(NPAIRS * 64 + 255) / 256, 256, 0, stream>>>(pairs, Dv, h1, z);
    hg7_zwin<<<(HB * HE2 * 64 + 255) / 256, 256, 0, stream>>>(h1, z);
    hg7_zero_h2<<<(HB * HN * HC + 255) / 256, 256, 0, stream>>>(h2);
    hg7_gscatter<<<(NPAIRS * 64 + 255) / 256, 256, 0, stream>>>(pairs, z, h2);
    hg7_gfinish<<<(HB * HN * 64 + 255) / 256, 256, 0, stream>>>(z, indeg, h2);
    hg7_bnstats<<<256, 256, 0, stream>>>(h2, bnsum, bnss);
    hg7_final<<<(HB * HN * HC) / 256, 256, 0, stream>>>(h2, x, gamma, beta, bnsum, bnss, out);
}

// Round 8
// 628.607 us; speedup vs baseline: 2.9868x; 1.0720x over previous
//
#include <hip/hip_runtime.h>

// HGNN layer, v8 — fp32. v7 structure with register-resident kNN selection:
// row loaded once into 36 orderable-uint32 keys/lane, extraction in strictly
// increasing (key,m) order (no invalidation, no LDS in the loop), 44-bit
// packed butterfly. B=4, N=2304, C=64.

#define HB    4
#define HN    2304
#define HC    64
#define HK    11             // K_NEIGS + 1
#define HL    48
#define HW    22             // windows per dim
#define HE2   484            // 22*22 local edges
#define HE    (HN + HE2)
#define HRPB  4              // rows per block == waves per block
#define NPAIRS (HB * HK * HN)   // sum of Dv == 11*N per batch, exact
#define NSLOT  (HN / 64)        // 36 keys per lane

__global__ void hg8_sentinel(float* out, int n) {
    int i = blockIdx.x * 256 + threadIdx.x;
    if (i < n) out[i] = 12345.0f;
}

__global__ void hg8_init(int* Dv, int* indeg, int* paircnt, float* bnsum, float* bnss) {
    int i = blockIdx.x * 256 + threadIdx.x;
    if (i < HB * HN) { Dv[i] = 0; indeg[i] = 0; }
    if (i == 0) *paircnt = 0;
    if (i < HC) { bnsum[i] = 0.f; bnss[i] = 0.f; }
}

// -------- linear h1 = x W^T + b, xsq, f32 transpose -----------------------
__global__ __launch_bounds__(64) void hg8_linear(const float* x, const float* W,
                                                 const float* bias, float* h1,
                                                 float* xsq, float* xT) {
    int row = blockIdx.x;            // 0..B*N-1
    int t = threadIdx.x;
    __shared__ float xr[HC];
    float v = x[row * HC + t];
    xr[t] = v;
    __syncthreads();
    float sq = v * v;
    #pragma unroll
    for (int o = 32; o > 0; o >>= 1) sq += __shfl_xor(sq, o);
    if (t == 0) xsq[row] = sq;
    int b = row / HN, n = row % HN;
    xT[(b * HC + t) * HN + n] = v;
    float acc = bias[t];
    #pragma unroll 8
    for (int c = 0; c < HC; c++) acc += xr[c] * W[t * HC + c];
    h1[row * HC + t] = acc;
}

// -------- kNN: block-cooperative distances, register-resident selection ---
// SEL=0: pick 11 nearest per row (incl self), count Dv[neighbor].
// SEL=1: pick Dv[row] nearest, emit (b,p,m) pairs, count node in-degree.
__device__ __forceinline__ void hg8_knn_body(const float* xT, const float* xsq,
                                             int* Dv, int* indeg,
                                             unsigned int* pairs, int* paircnt,
                                             int SEL) {
    __shared__ float d[HRPB][HN];      // 36 KB
    __shared__ float xr[HRPB][HC];
    const int t = threadIdx.x;
    const int b = blockIdx.x / (HN / HRPB);
    const int n0 = (blockIdx.x % (HN / HRPB)) * HRPB;
    xr[t >> 6][t & 63] = xT[(b * HC + (t & 63)) * HN + n0 + (t >> 6)];
    __syncthreads();
    float xs[HRPB];
    #pragma unroll
    for (int r = 0; r < HRPB; r++) xs[r] = xsq[b * HN + n0 + r];
    // distance phase: identical arithmetic/order to v7 (keeps selection stable)
    for (int m = t; m < HN; m += 256) {          // 9 iterations
        float dot0 = 0.f, dot1 = 0.f, dot2 = 0.f, dot3 = 0.f;
        #pragma unroll 8
        for (int c = 0; c < HC; c++) {
            float xv = xT[(b * HC + c) * HN + m];
            dot0 += xr[0][c] * xv;
            dot1 += xr[1][c] * xv;
            dot2 += xr[2][c] * xv;
            dot3 += xr[3][c] * xv;
        }
        float xsm = xsq[b * HN + m];
        d[0][m] = xs[0] + xsm - 2.f * dot0;
        d[1][m] = xs[1] + xsm - 2.f * dot1;
        d[2][m] = xs[2] + xsm - 2.f * dot2;
        d[3][m] = xs[3] + xsm - 2.f * dot3;
    }
    __syncthreads();

    // ---- selection: wave r owns row r; all state in registers.
    const int r = t >> 6;
    const int lane = t & 63;
    const int p = n0 + r;
    const int kk = SEL ? max(Dv[b * HN + p], 1) : HK;
    int base = 0;
    if (SEL) {                                   // reserve kk pair slots once
        if (lane == 0) base = atomicAdd(paircnt, kk);
        base = __shfl(base, 0);
    }
    // load row once; order-preserving uint32 keys (handles negatives)
    unsigned int key[NSLOT];
    const float2* drow = (const float2*)d[r];
    #pragma unroll
    for (int i = 0; i < NSLOT / 2; i++) {
        float2 f = drow[lane + 64 * i];
        unsigned int bx = __float_as_uint(f.x);
        unsigned int by = __float_as_uint(f.y);
        key[2 * i]     = bx ^ (((unsigned)((int)bx >> 31)) | 0x80000000u);
        key[2 * i + 1] = by ^ (((unsigned)((int)by >> 31)) | 0x80000000u);
    }
    // element j (slot) has global index m = 2*(lane + 64*(j/2)) + (j&1)
    unsigned long long last = 0;                 // all real packed keys are > 0
    const unsigned long long UMAX = ~0ull;
    for (int j = 0; j < kk; j++) {
        unsigned long long a0 = UMAX, a1 = UMAX, a2 = UMAX, a3 = UMAX;
        #pragma unroll
        for (int i = 0; i < NSLOT / 4; i++) {    // 4 independent chains
            #pragma unroll
            for (int q = 0; q < 4; q++) {
                int s = 4 * i + q;
                int m = 2 * (lane + 64 * (s >> 1)) + (s & 1);
                unsigned long long ku =
                    ((unsigned long long)key[s] << 12) | (unsigned)m;
                unsigned long long cand = (ku > last) ? ku : UMAX;
                if (q == 0) { if (cand < a0) a0 = cand; }
                else if (q == 1) { if (cand < a1) a1 = cand; }
                else if (q == 2) { if (cand < a2) a2 = cand; }
                else             { if (cand < a3) a3 = cand; }
            }
        }
        unsigned long long m01 = a0 < a1 ? a0 : a1;
        unsigned long long m23 = a2 < a3 ? a2 : a3;
        unsigned long long best = m01 < m23 ? m01 : m23;
        #pragma unroll
        for (int o = 32; o > 0; o >>= 1) {       // packed key: one u64 min
            unsigned long long ob = __shfl_xor(best, o);
            if (ob < best) best = ob;
        }
        last = best;                             // wave-uniform
        if (lane == 0) {
            int bi = (int)(best & 0xFFFu);
            if (SEL) {
                atomicAdd(&indeg[b * HN + bi], 1);
                pairs[base + j] = ((unsigned)b << 24) | ((unsigned)p << 12) | (unsigned)bi;
            } else {
                atomicAdd(&Dv[b * HN + bi], 1);
            }
        }
    }
}

__global__ __launch_bounds__(256) void hg8_knn_count(const float* xT, const float* xsq,
                                                     int* Dv, int* indeg,
                                                     unsigned int* pairs, int* paircnt) {
    hg8_knn_body(xT, xsq, Dv, indeg, pairs, paircnt, 0);
}

__global__ __launch_bounds__(256) void hg8_knn_select(const float* xT, const float* xsq,
                                                      int* Dv, int* indeg,
                                                      unsigned int* pairs, int* paircnt) {
    hg8_knn_body(xT, xsq, Dv, indeg, pairs, paircnt, 1);
}

__device__ __forceinline__ int hg8_lo(int rc) { return max(0, (rc - 3) / 2); }
__device__ __forceinline__ int hg8_hi(int rc) { return min(HW - 1, rc / 2); }

// -------- y = Dv^-1/2 * h1 (in place) -------------------------------------
__global__ __launch_bounds__(256) void hg8_scale(float* h1, const int* indeg) {
    int i = blockIdx.x * 256 + threadIdx.x;
    int node = i >> 6;
    int n = node % HN;
    int r = n / HL, c = n % HL;
    int cover = max(0, hg8_hi(r) - hg8_lo(r) + 1) * max(0, hg8_hi(c) - hg8_lo(c) + 1);
    int dvn = max(indeg[node] + cover, 1);
    h1[i] *= rsqrtf((float)dvn);
}

// -------- zero z (kNN-edge part) and h2, one kernel -----------------------
__global__ void hg8_zero(float* z, float* h2) {
    int i = blockIdx.x * 256 + threadIdx.x;      // over B*N*C
    int b = i / (HN * HC), rem = i % (HN * HC);
    z[b * HE * HC + rem] = 0.f;                  // window part written by edge kernel
    h2[i] = 0.f;
}

// -------- fused edge kernel: kNN scatter + window means -------------------
__global__ __launch_bounds__(256) void hg8_edge(const unsigned int* pairs, const int* Dv,
                                                const float* y, float* z) {
    int wv = (blockIdx.x * 256 + threadIdx.x) >> 6;
    int lane = threadIdx.x & 63;
    if (wv < NPAIRS) {
        unsigned int pk = pairs[wv];
        int b = pk >> 24;
        if (b >= HB) return;                     // defensive (poison)
        int p = (pk >> 12) & 0xFFF, m = pk & 0xFFF;
        float invde = 1.f / (float)max(Dv[b * HN + p], 1);
        atomicAdd(&z[(b * HE + p) * HC + lane], y[(b * HN + m) * HC + lane] * invde);
    } else {
        int w2 = wv - NPAIRS;
        if (w2 >= HB * HE2) return;
        int b = w2 / HE2, w = w2 % HE2;
        int wr = w / HW, wc = w % HW;
        float acc = 0.f;
        #pragma unroll
        for (int i = 0; i < 5; i++)
            #pragma unroll
            for (int j = 0; j < 5; j++)
                acc += y[(b * HN + (wr * 2 + i) * HL + wc * 2 + j) * HC + lane];
        z[(b * HE + HN + w) * HC + lane] = acc * (1.f / 25.f);
    }
}

// -------- h2[m] += z[p] over the pair list (atomic) -----------------------
__global__ __launch_bounds__(256) void hg8_gscatter(const unsigned int* pairs,
                                                    const float* z, float* h2) {
    int idx = (blockIdx.x * 256 + threadIdx.x) >> 6;
    int lane = threadIdx.x & 63;
    if (idx >= NPAIRS) return;
    unsigned int pk = pairs[idx];
    int b = pk >> 24;
    if (b >= HB) return;                         // defensive (poison)
    int p = (pk >> 12) & 0xFFF, m = pk & 0xFFF;
    atomicAdd(&h2[(b * HN + m) * HC + lane], z[(b * HE + p) * HC + lane]);
}

// -------- add window contributions + final Dv^-1/2 scale ------------------
__global__ __launch_bounds__(256) void hg8_gfinish(const float* z, const int* indeg, float* h2) {
    int wave = (blockIdx.x * 256 + threadIdx.x) >> 6;  // one wave per (b, node)
    int lane = threadIdx.x & 63;
    int b = wave / HN, n = wave % HN;
    int g = b * HN + n;
    float acc = h2[g * HC + lane];
    int r = n / HL, c = n % HL;
    int rlo = hg8_lo(r), rhi = hg8_hi(r), clo = hg8_lo(c), chi = hg8_hi(c);
    for (int wr = rlo; wr <= rhi; wr++)
        for (int wc = clo; wc <= chi; wc++)
            acc += z[(b * HE + HN + wr * HW + wc) * HC + lane];
    int dvn = max(indeg[g] + max(0, rhi - rlo + 1) * max(0, chi - clo + 1), 1);
    h2[g * HC + lane] = acc * rsqrtf((float)dvn);
}

// -------- BN stats --------------------------------------------------------
__global__ __launch_bounds__(256) void hg8_bnstats(const float* h2, float* bnsum, float* bnss) {
    int t = threadIdx.x;
    int c = t & 63, rg = t >> 6;
    int row0 = blockIdx.x * 36;      // 256 blocks * 36 rows = 9216
    float s = 0.f, ss = 0.f;
    for (int r = rg; r < 36; r += 4) {
        float v = h2[(row0 + r) * HC + c];
        s += v; ss += v * v;
    }
    __shared__ float ls[256], lss[256];
    ls[t] = s; lss[t] = ss;
    __syncthreads();
    if (t < 64) {
        s  = ls[t]  + ls[t + 64]  + ls[t + 128]  + ls[t + 192];
        ss = lss[t] + lss[t + 64] + lss[t + 128] + lss[t + 192];
        atomicAdd(&bnsum[t], s);
        atomicAdd(&bnss[t], ss);
    }
}

// -------- BN + ReLU + residual --------------------------------------------
__global__ __launch_bounds__(256) void hg8_final(const float* h2, const float* x,
                                                 const float* gamma, const float* beta,
                                                 const float* bnsum, const float* bnss,
                                                 float* out) {
    int i = blockIdx.x * 256 + threadIdx.x;
    int c = i & 63;
    const float M = (float)(HB * HN);
    float mean = bnsum[c] / M;
    float var  = bnss[c] / M - mean * mean;
    float inv  = rsqrtf(var + 1e-5f);
    float h = gamma[c] * (h2[i] - mean) * inv + beta[c];
    out[i] = fmaxf(h, 0.f) + x[i];
}

extern "C" void kernel_launch(void* const* d_in, const int* in_sizes, int n_in,
                              void* d_out, int out_size, void* d_ws, size_t ws_size,
                              hipStream_t stream) {
    const float* x     = (const float*)d_in[0];
    const float* W     = (const float*)d_in[1];
    const float* bias  = (const float*)d_in[2];
    const float* gamma = (const float*)d_in[3];
    const float* beta  = (const float*)d_in[4];
    float* out = (float*)d_out;
    (void)in_sizes; (void)n_in;

    char* ws = (char*)d_ws;
    size_t off = 0;
    float*        xsq     = (float*)(ws + off);        off += (size_t)HB * HN * 4;
    float*        h1      = (float*)(ws + off);        off += (size_t)HB * HN * HC * 4;
    float*        h2      = (float*)(ws + off);        off += (size_t)HB * HN * HC * 4;
    int*          Dv      = (int*)(ws + off);          off += (size_t)HB * HN * 4;
    int*          indeg   = (int*)(ws + off);          off += (size_t)HB * HN * 4;
    unsigned int* pairs   = (unsigned int*)(ws + off); off += (size_t)NPAIRS * 4;
    float*        bnsum   = (float*)(ws + off);        off += 256;
    float*        bnss    = (float*)(ws + off);        off += 256;
    int*          paircnt = (int*)(ws + off);          off += 256;
    float*        xT      = (float*)(ws + off);        // z aliases xT (dead after kNN)
    float*        z       = (float*)(ws + off);
    off += (size_t)HB * HE * HC * 4;   // max(xT, z) = z

    if (ws_size < off) {
        hg8_sentinel<<<(out_size + 255) / 256, 256, 0, stream>>>(out, out_size);
        return;
    }

    const int EDGE_WAVES = NPAIRS + HB * HE2;    // 103312, divisible by 4

    hg8_init<<<(HB * HN + 255) / 256, 256, 0, stream>>>(Dv, indeg, paircnt, bnsum, bnss);
    hg8_linear<<<HB * HN, 64, 0, stream>>>(x, W, bias, h1, xsq, xT);
    hg8_knn_count<<<HB * (HN / HRPB), 256, 0, stream>>>(xT, xsq, Dv, indeg, pairs, paircnt);
    hg8_knn_select<<<HB * (HN / HRPB), 256, 0, stream>>>(xT, xsq, Dv, indeg, pairs, paircnt);
    hg8_scale<<<(HB * HN * HC) / 256, 256, 0, stream>>>(h1, indeg);
    hg8_zero<<<(HB * HN * HC) / 256, 256, 0, stream>>>(z, h2);
    hg8_edge<<<EDGE_WAVES / 4, 256, 0, stream>>>(pairs, Dv, h1, z);
    hg8_gscatter<<<(NPAIRS * 64) / 256, 256, 0, stream>>>(pairs, z, h2);
    hg8_gfinish<<<(HB * HN) / 4, 256, 0, stream>>>(z, indeg, h2);
    hg8_bnstats<<<256, 256, 0, stream>>>(h2, bnsum, bnss);
    hg8_final<<<(HB * HN * HC) / 256, 256, 0, stream>>>(h2, x, gamma, beta, bnsum, bnss, out);
}